// Round 1
// baseline (284.348 us; speedup 1.0000x reference)
//
#include <hip/hip_runtime.h>
#include <hip/hip_bf16.h>

// MHA: B=2, T=2048, C=1024, H=16, Dh=64. fp32 in/out, bf16 MFMA internally.
// ws layout (bf16 elems): xb[4M] wq[1M] wk[1M] wv[1M] wo[1M] Q[4M] K[4M] V[4M] AO[4M] = 48 MB.

typedef __bf16 bf16;
typedef __attribute__((ext_vector_type(8))) __bf16 bf16x8;
typedef __attribute__((ext_vector_type(4))) __bf16 bf16x4;
typedef __attribute__((ext_vector_type(4))) float floatx4;
typedef __attribute__((ext_vector_type(8))) unsigned short ushort8;

#define LOG2E 1.44269504088896340736f

__device__ __forceinline__ void gl2lds16(const void* g, void* l) {
  __builtin_amdgcn_global_load_lds((const __attribute__((address_space(1))) void*)g,
                                   (__attribute__((address_space(3))) void*)l, 16, 0, 0);
}

// ---------------- cast fp32 -> bf16 (x | wq | wk | wv | wo) ----------------
__global__ __launch_bounds__(256) void cast_all(
    const float* __restrict__ x, const float* __restrict__ wq,
    const float* __restrict__ wk, const float* __restrict__ wv,
    const float* __restrict__ wo, bf16* __restrict__ dst)
{
  const size_t M1 = (size_t)1 << 20;
  size_t i4 = ((size_t)blockIdx.x * 256 + threadIdx.x) * 4;
  const float* src = x;
  size_t off = i4;
  if (i4 >= 4 * M1) {
    size_t r = i4 - 4 * M1;
    int seg = (int)(r >> 20);
    off = r & (M1 - 1);
    src = (seg == 0) ? wq : (seg == 1) ? wk : (seg == 2) ? wv : wo;
  }
  float4 f = *(const float4*)(src + off);
  bf16x4 o = { (bf16)f.x, (bf16)f.y, (bf16)f.z, (bf16)f.w };
  *(bf16x4*)(dst + i4) = o;
}

// ---------------- GEMM: out[m][n] = sum_k A[m][k]*W[n][k] + bias[n] ----------------
// m97 structure: 128x128 tile, BK=32, global_load_lds(16B), 16 MFMA/K-step.
template<bool F32OUT, bool QKV>
__global__ __launch_bounds__(256, 2) void gemm_bt(
    const bf16* __restrict__ A, const bf16* __restrict__ Wb,
    const float* __restrict__ bq, const float* __restrict__ bk,
    const float* __restrict__ bv, void* __restrict__ outb,
    int M, int N, int K, float qscale)
{
  __shared__ bf16 As[128 * 32];
  __shared__ bf16 Bs[128 * 32];
  const int tid = threadIdx.x;
  const int lane = tid & 63;
  const int wid = tid >> 6;
  const int wr = wid >> 1, wc = wid & 1;
  const int l15 = lane & 15, l4 = lane >> 4;

  const bf16* W;
  const float* bias;
  float osc = 1.0f;
  int n0;
  bf16* outh;
  float* outf;
  if (QKV) {
    int mat = blockIdx.x >> 3;
    n0 = (blockIdx.x & 7) << 7;
    W = Wb + ((size_t)mat << 20);
    bias = (mat == 0) ? bq : (mat == 1 ? bk : bv);
    if (mat == 0) osc = qscale;
    outh = (bf16*)outb + ((size_t)mat << 22);
    outf = nullptr;
  } else {
    n0 = blockIdx.x << 7;
    W = Wb;
    bias = bq;
    outf = (float*)outb;
    outh = nullptr;
  }
  const int m0 = blockIdx.y << 7;

  floatx4 acc[4][4] = {};

  for (int k0 = 0; k0 < K; k0 += 32) {
#pragma unroll
    for (int it = 0; it < 2; ++it) {
      int c = it * 256 + tid;
      int row = c >> 2, kof = (c & 3) << 3;
      gl2lds16(A + (size_t)(m0 + row) * K + k0 + kof, As + c * 8);
      gl2lds16(W + (size_t)(n0 + row) * K + k0 + kof, Bs + c * 8);
    }
    __syncthreads();
    bf16x8 af[4], bfr[4];
#pragma unroll
    for (int i = 0; i < 4; ++i)
      af[i] = *(const bf16x8*)(As + (wr * 64 + i * 16 + l15) * 32 + l4 * 8);
#pragma unroll
    for (int j = 0; j < 4; ++j)
      bfr[j] = *(const bf16x8*)(Bs + (wc * 64 + j * 16 + l15) * 32 + l4 * 8);
#pragma unroll
    for (int i = 0; i < 4; ++i)
#pragma unroll
      for (int j = 0; j < 4; ++j)
        acc[i][j] = __builtin_amdgcn_mfma_f32_16x16x32_bf16(af[i], bfr[j], acc[i][j], 0, 0, 0);
    __syncthreads();
  }

#pragma unroll
  for (int j = 0; j < 4; ++j) {
    int col = n0 + wc * 64 + j * 16 + l15;
    float bv_ = bias[col];
#pragma unroll
    for (int i = 0; i < 4; ++i) {
#pragma unroll
      for (int rg = 0; rg < 4; ++rg) {
        int row = m0 + wr * 64 + i * 16 + l4 * 4 + rg;
        float v = (acc[i][j][rg] + bv_) * osc;
        if (F32OUT) outf[(size_t)row * N + col] = v;
        else        outh[(size_t)row * N + col] = (bf16)v;
      }
    }
  }
}

// ---------------- fused causal flash attention ----------------
// grid (16, 32): x -> q-tile (reversed, heavy first), y -> b*16+h.
// Q pre-scaled by 1/sqrt(Dh)*log2e, so p = exp2(s - m).
__global__ __launch_bounds__(256, 2) void attn_kernel(
    const bf16* __restrict__ Q, const bf16* __restrict__ Kg,
    const bf16* __restrict__ Vg, bf16* __restrict__ AO)
{
  constexpr int T = 2048, HD = 64, C = 1024;
  __shared__ bf16 Qs[128 * 64];   // xor-swizzled column groups
  __shared__ bf16 Ks[64 * 64];    // xor-swizzled column groups
  __shared__ bf16 Vts[64 * 72];   // V^T, padded (+8) rows
  __shared__ bf16 Ps[4][32 * 72]; // per-wave P, padded (+8) rows

  const int tid = threadIdx.x;
  const int lane = tid & 63;
  const int w = tid >> 6;
  const int l15 = lane & 15, l4 = lane >> 4;

  const int qt = (int)gridDim.x - 1 - (int)blockIdx.x;
  const int q0 = qt << 7;
  const int b = blockIdx.y >> 4, h = blockIdx.y & 15;
  const size_t base = ((size_t)b * T) * C + h * HD;

  // stage Q (128x64), swizzle: LDS[row][slot] <- global group slot^(row&7)
#pragma unroll
  for (int it = 0; it < 4; ++it) {
    int c = it * 256 + tid;
    int row = c >> 3, s = (c & 7) ^ (row & 7);
    gl2lds16(Q + base + (size_t)(q0 + row) * C + s * 8, Qs + c * 8);
  }

  floatx4 o[2][4] = {};
  float mrow[2][4], lrow[2][4];
#pragma unroll
  for (int ti = 0; ti < 2; ++ti)
#pragma unroll
    for (int rg = 0; rg < 4; ++rg) { mrow[ti][rg] = -1e38f; lrow[ti][rg] = 0.f; }

  const int nkt = 2 * qt + 2;
  for (int jt = 0; jt < nkt; ++jt) {
    const int j0 = jt << 6;
    // stage K tile (64x64), swizzled
#pragma unroll
    for (int it = 0; it < 2; ++it) {
      int c = it * 256 + tid;
      int row = c >> 3, s = (c & 7) ^ (row & 7);
      gl2lds16(Kg + base + (size_t)(j0 + row) * C + s * 8, Ks + c * 8);
    }
    // stage V^T: Vts[d][j], 8 coalesced u16 loads -> one ds_write_b128
    {
      const int dcol = tid & 63, jg = tid >> 6;
#pragma unroll
      for (int it = 0; it < 2; ++it) {
        int jb = (it * 4 + jg) * 8;
        ushort8 tmp;
#pragma unroll
        for (int jj = 0; jj < 8; ++jj)
          tmp[jj] = *(const unsigned short*)(Vg + base + (size_t)(j0 + jb + jj) * C + dcol);
        *(ushort8*)(&Vts[dcol * 72 + jb]) = tmp;
      }
    }
    __syncthreads();

    if (j0 <= q0 + w * 32 + 31) {  // wave-uniform: skip fully-masked tiles
      // S = Q K^T : per wave rows w*32..+32, cols j0..j0+63
      floatx4 s4[2][4] = {};
#pragma unroll
      for (int kk = 0; kk < 2; ++kk) {
        bf16x8 aq[2], bk8[4];
#pragma unroll
        for (int ti = 0; ti < 2; ++ti) {
          int r = w * 32 + ti * 16 + l15;
          int sl = (kk * 4 + l4) ^ (r & 7);
          aq[ti] = *(const bf16x8*)(Qs + r * 64 + sl * 8);
        }
#pragma unroll
        for (int tj = 0; tj < 4; ++tj) {
          int r = tj * 16 + l15;
          int sl = (kk * 4 + l4) ^ (r & 7);
          bk8[tj] = *(const bf16x8*)(Ks + r * 64 + sl * 8);
        }
#pragma unroll
        for (int ti = 0; ti < 2; ++ti)
#pragma unroll
          for (int tj = 0; tj < 4; ++tj)
            s4[ti][tj] = __builtin_amdgcn_mfma_f32_16x16x32_bf16(aq[ti], bk8[tj], s4[ti][tj], 0, 0, 0);
      }

      // causal mask (only near diagonal)
      if (j0 + 63 > q0 + w * 32) {
#pragma unroll
        for (int ti = 0; ti < 2; ++ti) {
          int qrow = q0 + w * 32 + ti * 16 + l4 * 4;
#pragma unroll
          for (int tj = 0; tj < 4; ++tj) {
            int kcol = j0 + tj * 16 + l15;
#pragma unroll
            for (int rg = 0; rg < 4; ++rg)
              if (kcol > qrow + rg) s4[ti][tj][rg] = -3e38f;
          }
        }
      }

      // online softmax (rows live in 16-lane groups; C layout row = l4*4+rg)
#pragma unroll
      for (int ti = 0; ti < 2; ++ti) {
#pragma unroll
        for (int rg = 0; rg < 4; ++rg) {
          float mx = fmaxf(fmaxf(s4[ti][0][rg], s4[ti][1][rg]),
                           fmaxf(s4[ti][2][rg], s4[ti][3][rg]));
#pragma unroll
          for (int off = 1; off < 16; off <<= 1)
            mx = fmaxf(mx, __shfl_xor(mx, off, 64));
          float mnew = fmaxf(mrow[ti][rg], mx);
          float alpha = exp2f(mrow[ti][rg] - mnew);
          mrow[ti][rg] = mnew;
          float psum = 0.f;
#pragma unroll
          for (int tj = 0; tj < 4; ++tj) {
            float p = exp2f(s4[ti][tj][rg] - mnew);
            s4[ti][tj][rg] = p;
            psum += p;
          }
#pragma unroll
          for (int off = 1; off < 16; off <<= 1)
            psum += __shfl_xor(psum, off, 64);
          lrow[ti][rg] = lrow[ti][rg] * alpha + psum;
#pragma unroll
          for (int td = 0; td < 4; ++td)
            o[ti][td][rg] *= alpha;
        }
      }

      // P -> LDS (C layout -> A-operand layout via round-trip)
#pragma unroll
      for (int ti = 0; ti < 2; ++ti)
#pragma unroll
        for (int tj = 0; tj < 4; ++tj)
#pragma unroll
          for (int rg = 0; rg < 4; ++rg)
            Ps[w][(ti * 16 + l4 * 4 + rg) * 72 + tj * 16 + l15] = (bf16)s4[ti][tj][rg];

      // O += P V
#pragma unroll
      for (int tk = 0; tk < 2; ++tk) {
        bf16x8 ap[2], bv8[4];
#pragma unroll
        for (int ti = 0; ti < 2; ++ti)
          ap[ti] = *(const bf16x8*)(&Ps[w][(ti * 16 + l15) * 72 + tk * 32 + l4 * 8]);
#pragma unroll
        for (int td = 0; td < 4; ++td)
          bv8[td] = *(const bf16x8*)(&Vts[(td * 16 + l15) * 72 + tk * 32 + l4 * 8]);
#pragma unroll
        for (int ti = 0; ti < 2; ++ti)
#pragma unroll
          for (int td = 0; td < 4; ++td)
            o[ti][td] = __builtin_amdgcn_mfma_f32_16x16x32_bf16(ap[ti], bv8[td], o[ti][td], 0, 0, 0);
      }
    }
    __syncthreads();
  }

  // epilogue: O / l -> AO (bf16)
#pragma unroll
  for (int ti = 0; ti < 2; ++ti)
#pragma unroll
    for (int rg = 0; rg < 4; ++rg) {
      float inv = 1.0f / lrow[ti][rg];
      int qrow = q0 + w * 32 + ti * 16 + l4 * 4 + rg;
#pragma unroll
      for (int td = 0; td < 4; ++td)
        AO[base + (size_t)qrow * C + td * 16 + l15] = (bf16)(o[ti][td][rg] * inv);
    }
}

// ---------------- launch ----------------
extern "C" void kernel_launch(void* const* d_in, const int* in_sizes, int n_in,
                              void* d_out, int out_size, void* d_ws, size_t ws_size,
                              hipStream_t stream) {
  const float* x  = (const float*)d_in[0];
  const float* Wq = (const float*)d_in[1];
  const float* bq = (const float*)d_in[2];
  const float* Wk = (const float*)d_in[3];
  const float* bk = (const float*)d_in[4];
  const float* Wv = (const float*)d_in[5];
  const float* bv = (const float*)d_in[6];
  const float* Wo = (const float*)d_in[7];
  const float* bo = (const float*)d_in[8];

  bf16* ws = (bf16*)d_ws;
  const size_t M1 = (size_t)1 << 20;
  bf16* xb  = ws;            // 4M
  bf16* wqb = ws + 4 * M1;   // wq|wk|wv (1M each)
  bf16* wob = ws + 7 * M1;   // 1M
  bf16* Qp  = ws + 8 * M1;   // Q|K|V (4M each)
  bf16* AOp = ws + 20 * M1;  // 4M   (total 24M bf16 = 48 MB <= ws_size)

  // 1) cast inputs to bf16
  cast_all<<<8192, 256, 0, stream>>>(x, Wq, Wk, Wv, Wo, ws);
  // 2) fused QKV projection (Q pre-scaled by 1/sqrt(64)*log2e)
  gemm_bt<false, true><<<dim3(24, 32), 256, 0, stream>>>(
      xb, wqb, bq, bk, bv, (void*)Qp, 4096, 1024, 1024, 0.125f * LOG2E);
  // 3) causal flash attention
  attn_kernel<<<dim3(16, 32), 256, 0, stream>>>(Qp, Qp + 4 * M1, Qp + 8 * M1, AOp);
  // 4) output projection (fp32 out + bias)
  gemm_bt<true, false><<<dim3(8, 32), 256, 0, stream>>>(
      AOp, wob, bo, nullptr, nullptr, d_out, 4096, 1024, 1024, 1.0f);
}

// Round 2
// 251.786 us; speedup vs baseline: 1.1293x; 1.1293x over previous
//
#include <hip/hip_runtime.h>
#include <hip/hip_bf16.h>

// MHA: B=2, T=2048, C=1024, H=16, Dh=64. fp32 in/out, bf16 MFMA internally.
// ws layout (bf16 elems): xb[4M] wq[1M] wk[1M] wv[1M] wo[1M] Q[4M] K[4M] V[4M] AO[4M] = 48 MB.

typedef __bf16 bf16;
typedef __attribute__((ext_vector_type(8))) __bf16 bf16x8;
typedef __attribute__((ext_vector_type(4))) __bf16 bf16x4;
typedef __attribute__((ext_vector_type(4))) float floatx4;
typedef __attribute__((ext_vector_type(8))) unsigned short ushort8;

#define LOG2E 1.44269504088896340736f

__device__ __forceinline__ void gl2lds16(const void* g, void* l) {
  __builtin_amdgcn_global_load_lds((const __attribute__((address_space(1))) void*)g,
                                   (__attribute__((address_space(3))) void*)l, 16, 0, 0);
}

// ---------------- cast fp32 -> bf16 (x | wq | wk | wv | wo) ----------------
__global__ __launch_bounds__(256) void cast_all(
    const float* __restrict__ x, const float* __restrict__ wq,
    const float* __restrict__ wk, const float* __restrict__ wv,
    const float* __restrict__ wo, bf16* __restrict__ dst)
{
  const size_t M1 = (size_t)1 << 20;
  size_t i4 = ((size_t)blockIdx.x * 256 + threadIdx.x) * 4;
  const float* src = x;
  size_t off = i4;
  if (i4 >= 4 * M1) {
    size_t r = i4 - 4 * M1;
    int seg = (int)(r >> 20);
    off = r & (M1 - 1);
    src = (seg == 0) ? wq : (seg == 1) ? wk : (seg == 2) ? wv : wo;
  }
  float4 f = *(const float4*)(src + off);
  bf16x4 o = { (bf16)f.x, (bf16)f.y, (bf16)f.z, (bf16)f.w };
  *(bf16x4*)(dst + i4) = o;
}

// ---------------- GEMM: out[m][n] = sum_k A[m][k]*W[n][k] + bias[n] ----------------
// m97 structure: 128xBN tile, BK=32, global_load_lds(16B).
template<bool F32OUT, bool QKV, int BN>
__global__ __launch_bounds__(256, 2) void gemm_bt(
    const bf16* __restrict__ A, const bf16* __restrict__ Wb,
    const float* __restrict__ bq, const float* __restrict__ bk,
    const float* __restrict__ bv, void* __restrict__ outb,
    int M, int N, int K, float qscale)
{
  __shared__ bf16 As[128 * 32];
  __shared__ bf16 Bs[BN * 32];
  const int tid = threadIdx.x;
  const int lane = tid & 63;
  const int wid = tid >> 6;
  const int l15 = lane & 15, l4 = lane >> 4;
  constexpr int I = (BN == 128) ? 4 : 2;
  const int wr = (BN == 128) ? (wid >> 1) : wid;
  const int wc = (BN == 128) ? (wid & 1) : 0;

  const bf16* W;
  const float* bias;
  float osc = 1.0f;
  int n0;
  bf16* outh;
  float* outf;
  if (QKV) {
    int mat = blockIdx.x >> 3;
    n0 = (blockIdx.x & 7) << 7;
    W = Wb + ((size_t)mat << 20);
    bias = (mat == 0) ? bq : (mat == 1 ? bk : bv);
    if (mat == 0) osc = qscale;
    outh = (bf16*)outb + ((size_t)mat << 22);
    outf = nullptr;
  } else {
    n0 = blockIdx.x * BN;
    W = Wb;
    bias = bq;
    outf = (float*)outb;
    outh = nullptr;
  }
  const int m0 = blockIdx.y << 7;

  floatx4 acc[I][4] = {};

  for (int k0 = 0; k0 < K; k0 += 32) {
#pragma unroll
    for (int it = 0; it < 2; ++it) {
      int c = it * 256 + tid;
      int row = c >> 2, kof = (c & 3) << 3;
      gl2lds16(A + (size_t)(m0 + row) * K + k0 + kof, As + c * 8);
    }
#pragma unroll
    for (int it = 0; it < BN / 64; ++it) {
      int c = it * 256 + tid;
      int row = c >> 2, kof = (c & 3) << 3;
      gl2lds16(W + (size_t)(n0 + row) * K + k0 + kof, Bs + c * 8);
    }
    __syncthreads();
    bf16x8 af[I], bfr[4];
#pragma unroll
    for (int i = 0; i < I; ++i)
      af[i] = *(const bf16x8*)(As + (wr * (I * 16) + i * 16 + l15) * 32 + l4 * 8);
#pragma unroll
    for (int j = 0; j < 4; ++j)
      bfr[j] = *(const bf16x8*)(Bs + (wc * 64 + j * 16 + l15) * 32 + l4 * 8);
#pragma unroll
    for (int i = 0; i < I; ++i)
#pragma unroll
      for (int j = 0; j < 4; ++j)
        acc[i][j] = __builtin_amdgcn_mfma_f32_16x16x32_bf16(af[i], bfr[j], acc[i][j], 0, 0, 0);
    __syncthreads();
  }

#pragma unroll
  for (int j = 0; j < 4; ++j) {
    int col = n0 + wc * 64 + j * 16 + l15;
    float bv_ = bias[col];
#pragma unroll
    for (int i = 0; i < I; ++i) {
#pragma unroll
      for (int rg = 0; rg < 4; ++rg) {
        int row = m0 + wr * (I * 16) + i * 16 + l4 * 4 + rg;
        float v = (acc[i][j][rg] + bv_) * osc;
        if (F32OUT) outf[(size_t)row * N + col] = v;
        else        outh[(size_t)row * N + col] = (bf16)v;
      }
    }
  }
}

// ---------------- fused causal flash attention ----------------
// grid (32, 32): x -> q-tile (reversed, heavy first), y -> b*16+h.
// 64 q-rows/block (16/wave, in registers), K-tile 64, double-buffered staging,
// ONE barrier per K-tile. Row-sum via MFMA ones-trick. Q pre-scaled by
// 1/sqrt(Dh)*log2e so p = exp2(s - m).
__global__ __launch_bounds__(256, 3) void attn_kernel(
    const bf16* __restrict__ Q, const bf16* __restrict__ Kg,
    const bf16* __restrict__ Vg, bf16* __restrict__ AO)
{
  constexpr int T = 2048, C = 1024;
  __shared__ bf16 Ks[2][64 * 64];   // xor-swizzled column groups
  __shared__ bf16 Vts[2][64 * 72];  // V^T, padded rows
  __shared__ bf16 Ps[4][16 * 72];   // per-wave P

  const int tid = threadIdx.x;
  const int lane = tid & 63;
  const int w = tid >> 6;
  const int l15 = lane & 15, l4 = lane >> 4;

  const int qt = 31 - (int)blockIdx.x;
  const int q0 = qt << 6;
  const int b = blockIdx.y >> 4, h = blockIdx.y & 15;
  const size_t base = ((size_t)b * T) * C + h * 64;

  // Q fragments in registers: wave w owns rows q0 + w*16 .. +15
  bf16x8 aq[2];
  {
    const bf16* qp = Q + base + (size_t)(q0 + w * 16 + l15) * C + l4 * 8;
    aq[0] = *(const bf16x8*)(qp);
    aq[1] = *(const bf16x8*)(qp + 32);
  }

  floatx4 o[4] = {};
  floatx4 lacc = {0.f, 0.f, 0.f, 0.f};
  float mrow[4] = {-1e38f, -1e38f, -1e38f, -1e38f};

  const bf16 one_h = (bf16)1.0f;
  const bf16x8 ones = {one_h, one_h, one_h, one_h, one_h, one_h, one_h, one_h};

  const int nkt = qt + 1;
  const int dcol = tid & 63, jg = tid >> 6;

  auto stageK = [&](int jt, int bufi) {
    const int j0 = jt << 6;
#pragma unroll
    for (int it = 0; it < 2; ++it) {
      int c = it * 256 + tid;
      int row = c >> 3, s = (c & 7) ^ (row & 7);
      gl2lds16(Kg + base + (size_t)(j0 + row) * C + s * 8, &Ks[bufi][c * 8]);
    }
  };
  auto loadV = [&](int jt, ushort8* vt) {
    const int j0 = jt << 6;
#pragma unroll
    for (int it = 0; it < 2; ++it) {
      int jb = (it * 4 + jg) * 8;
      ushort8 t;
#pragma unroll
      for (int jj = 0; jj < 8; ++jj)
        t[jj] = *(const unsigned short*)(Vg + base + (size_t)(j0 + jb + jj) * C + dcol);
      vt[it] = t;
    }
  };
  auto writeV = [&](int bufi, const ushort8* vt) {
#pragma unroll
    for (int it = 0; it < 2; ++it) {
      int jb = (it * 4 + jg) * 8;
      *(ushort8*)(&Vts[bufi][dcol * 72 + jb]) = vt[it];
    }
  };

  ushort8 vt[2];
  stageK(0, 0);
  loadV(0, vt);
  writeV(0, vt);

  for (int jt = 0; jt < nkt; ++jt) {
    __syncthreads();  // staging of tile jt visible; prev tile's LDS reads done
    const int cur = jt & 1;
    const bool more = (jt + 1 < nkt);
    if (more) { loadV(jt + 1, vt); stageK(jt + 1, cur ^ 1); }

    // ---- S = Q K^T (16 q-rows x 64 k-cols per wave) ----
    floatx4 s4[4] = {};
#pragma unroll
    for (int kk = 0; kk < 2; ++kk) {
      bf16x8 bk8[4];
#pragma unroll
      for (int tj = 0; tj < 4; ++tj) {
        int r = tj * 16 + l15;
        int sl = (kk * 4 + l4) ^ (r & 7);
        bk8[tj] = *(const bf16x8*)(&Ks[cur][r * 64 + sl * 8]);
      }
#pragma unroll
      for (int tj = 0; tj < 4; ++tj)
        s4[tj] = __builtin_amdgcn_mfma_f32_16x16x32_bf16(aq[kk], bk8[tj], s4[tj], 0, 0, 0);
    }

    // causal mask: only the diagonal (last) tile needs it
    if (jt == nkt - 1) {
      const int j0 = jt << 6;
      int qrowb = q0 + w * 16 + l4 * 4;
#pragma unroll
      for (int tj = 0; tj < 4; ++tj) {
        int kcol = j0 + tj * 16 + l15;
#pragma unroll
        for (int rg = 0; rg < 4; ++rg)
          if (kcol > qrowb + rg) s4[tj][rg] = -3e38f;
      }
    }

    // ---- online softmax: max via shuffles, sum deferred to MFMA ----
#pragma unroll
    for (int rg = 0; rg < 4; ++rg) {
      float mx = fmaxf(fmaxf(s4[0][rg], s4[1][rg]), fmaxf(s4[2][rg], s4[3][rg]));
#pragma unroll
      for (int off = 1; off < 16; off <<= 1)
        mx = fmaxf(mx, __shfl_xor(mx, off, 64));
      float mnew = fmaxf(mrow[rg], mx);
      float al = __builtin_amdgcn_exp2f(mrow[rg] - mnew);
      mrow[rg] = mnew;
#pragma unroll
      for (int tj = 0; tj < 4; ++tj)
        s4[tj][rg] = __builtin_amdgcn_exp2f(s4[tj][rg] - mnew);
      lacc[rg] *= al;
#pragma unroll
      for (int td = 0; td < 4; ++td)
        o[td][rg] *= al;
    }

    // ---- P -> LDS (C layout -> A-operand layout) ----
#pragma unroll
    for (int tj = 0; tj < 4; ++tj)
#pragma unroll
      for (int rg = 0; rg < 4; ++rg)
        Ps[w][(l4 * 4 + rg) * 72 + tj * 16 + l15] = (bf16)s4[tj][rg];

    // ---- O += P V ; l += P . 1 ----
#pragma unroll
    for (int tk = 0; tk < 2; ++tk) {
      bf16x8 ap = *(const bf16x8*)(&Ps[w][l15 * 72 + tk * 32 + l4 * 8]);
      lacc = __builtin_amdgcn_mfma_f32_16x16x32_bf16(ap, ones, lacc, 0, 0, 0);
#pragma unroll
      for (int td = 0; td < 4; ++td) {
        bf16x8 bv8 = *(const bf16x8*)(&Vts[cur][(td * 16 + l15) * 72 + tk * 32 + l4 * 8]);
        o[td] = __builtin_amdgcn_mfma_f32_16x16x32_bf16(ap, bv8, o[td], 0, 0, 0);
      }
    }

    if (more) writeV(cur ^ 1, vt);
  }

  // epilogue: O / l -> AO (bf16)
#pragma unroll
  for (int rg = 0; rg < 4; ++rg) {
    float inv = 1.0f / lacc[rg];
    int qrow = q0 + w * 16 + l4 * 4 + rg;
#pragma unroll
    for (int td = 0; td < 4; ++td)
      AO[base + (size_t)qrow * C + td * 16 + l15] = (bf16)(o[td][rg] * inv);
  }
}

// ---------------- launch ----------------
extern "C" void kernel_launch(void* const* d_in, const int* in_sizes, int n_in,
                              void* d_out, int out_size, void* d_ws, size_t ws_size,
                              hipStream_t stream) {
  const float* x  = (const float*)d_in[0];
  const float* Wq = (const float*)d_in[1];
  const float* bq = (const float*)d_in[2];
  const float* Wk = (const float*)d_in[3];
  const float* bk = (const float*)d_in[4];
  const float* Wv = (const float*)d_in[5];
  const float* bv = (const float*)d_in[6];
  const float* Wo = (const float*)d_in[7];
  const float* bo = (const float*)d_in[8];

  bf16* ws = (bf16*)d_ws;
  const size_t M1 = (size_t)1 << 20;
  bf16* xb  = ws;            // 4M
  bf16* wqb = ws + 4 * M1;   // wq|wk|wv (1M each)
  bf16* wob = ws + 7 * M1;   // 1M
  bf16* Qp  = ws + 8 * M1;   // Q|K|V (4M each)
  bf16* AOp = ws + 20 * M1;  // 4M   (total 24M bf16 = 48 MB <= ws_size)

  // 1) cast inputs to bf16
  cast_all<<<8192, 256, 0, stream>>>(x, Wq, Wk, Wv, Wo, ws);
  // 2) fused QKV projection (Q pre-scaled by 1/sqrt(64)*log2e)
  gemm_bt<false, true, 128><<<dim3(24, 32), 256, 0, stream>>>(
      xb, wqb, bq, bk, bv, (void*)Qp, 4096, 1024, 1024, 0.125f * LOG2E);
  // 3) causal flash attention (64-row q-tiles, heavy-first)
  attn_kernel<<<dim3(32, 32), 256, 0, stream>>>(Qp, Qp + 4 * M1, Qp + 8 * M1, AOp);
  // 4) output projection (fp32 out + bias), 128x64 tiles for 512 blocks
  gemm_bt<true, false, 64><<<dim3(16, 32), 256, 0, stream>>>(
      AOp, wob, bo, nullptr, nullptr, d_out, 4096, 1024, 1024, 1.0f);
}

// Round 4
// 206.869 us; speedup vs baseline: 1.3745x; 1.2171x over previous
//
#include <hip/hip_runtime.h>
#include <hip/hip_bf16.h>

// MHA: B=2, T=2048, C=1024, H=16, Dh=64. fp32 in/out, bf16 MFMA internally.
// ws layout (bf16 elems): [0,4M): xb, later reused as Vt. [4M,7M): wq|wk|wv.
// [7M,8M): wo. [8M,20M): Q|K|V. [20M,24M): AO.  Total 48 MB.

typedef __bf16 bf16;
typedef __attribute__((ext_vector_type(8))) __bf16 bf16x8;
typedef __attribute__((ext_vector_type(4))) __bf16 bf16x4;
typedef __attribute__((ext_vector_type(4))) float floatx4;
typedef __attribute__((ext_vector_type(8))) unsigned short us8;
typedef __attribute__((ext_vector_type(4))) unsigned short us4;

#define LOG2E 1.44269504088896340736f

__device__ __forceinline__ void gl2lds16(const void* g, void* l) {
  __builtin_amdgcn_global_load_lds((const __attribute__((address_space(1))) void*)g,
                                   (__attribute__((address_space(3))) void*)l, 16, 0, 0);
}

// ---------------- cast fp32 -> bf16 (x | wq | wk | wv | wo) ----------------
__global__ __launch_bounds__(256) void cast_all(
    const float* __restrict__ x, const float* __restrict__ wq,
    const float* __restrict__ wk, const float* __restrict__ wv,
    const float* __restrict__ wo, bf16* __restrict__ dst)
{
  const size_t M1 = (size_t)1 << 20;
  size_t i4 = ((size_t)blockIdx.x * 256 + threadIdx.x) * 4;
  const float* src = x;
  size_t off = i4;
  if (i4 >= 4 * M1) {
    size_t r = i4 - 4 * M1;
    int seg = (int)(r >> 20);
    off = r & (M1 - 1);
    src = (seg == 0) ? wq : (seg == 1) ? wk : (seg == 2) ? wv : wo;
  }
  float4 f = *(const float4*)(src + off);
  bf16x4 o = { (bf16)f.x, (bf16)f.y, (bf16)f.z, (bf16)f.w };
  *(bf16x4*)(dst + i4) = o;
}

// ---------------- GEMM: out[m][n] = sum_k A[m][k]*W[n][k] + bias[n] ----------------
template<bool F32OUT, bool QKV, int BN>
__global__ __launch_bounds__(256, 2) void gemm_bt(
    const bf16* __restrict__ A, const bf16* __restrict__ Wb,
    const float* __restrict__ bq, const float* __restrict__ bk,
    const float* __restrict__ bv, void* __restrict__ outb,
    int M, int N, int K, float qscale)
{
  __shared__ bf16 As[128 * 32];
  __shared__ bf16 Bs[BN * 32];
  const int tid = threadIdx.x;
  const int lane = tid & 63;
  const int wid = tid >> 6;
  const int l15 = lane & 15, l4 = lane >> 4;
  constexpr int I = (BN == 128) ? 4 : 2;
  const int wr = (BN == 128) ? (wid >> 1) : wid;
  const int wc = (BN == 128) ? (wid & 1) : 0;

  const bf16* W;
  const float* bias;
  float osc = 1.0f;
  int n0;
  bf16* outh;
  float* outf;
  if (QKV) {
    int mat = blockIdx.x >> 3;
    n0 = (blockIdx.x & 7) << 7;
    W = Wb + ((size_t)mat << 20);
    bias = (mat == 0) ? bq : (mat == 1 ? bk : bv);
    if (mat == 0) osc = qscale;
    outh = (bf16*)outb + ((size_t)mat << 22);
    outf = nullptr;
  } else {
    n0 = blockIdx.x * BN;
    W = Wb;
    bias = bq;
    outf = (float*)outb;
    outh = nullptr;
  }
  const int m0 = blockIdx.y << 7;

  floatx4 acc[I][4] = {};

  for (int k0 = 0; k0 < K; k0 += 32) {
#pragma unroll
    for (int it = 0; it < 2; ++it) {
      int c = it * 256 + tid;
      int row = c >> 2, kof = (c & 3) << 3;
      gl2lds16(A + (size_t)(m0 + row) * K + k0 + kof, As + c * 8);
    }
#pragma unroll
    for (int it = 0; it < BN / 64; ++it) {
      int c = it * 256 + tid;
      int row = c >> 2, kof = (c & 3) << 3;
      gl2lds16(W + (size_t)(n0 + row) * K + k0 + kof, Bs + c * 8);
    }
    __syncthreads();
    bf16x8 af[I], bfr[4];
#pragma unroll
    for (int i = 0; i < I; ++i)
      af[i] = *(const bf16x8*)(As + (wr * (I * 16) + i * 16 + l15) * 32 + l4 * 8);
#pragma unroll
    for (int j = 0; j < 4; ++j)
      bfr[j] = *(const bf16x8*)(Bs + (wc * 64 + j * 16 + l15) * 32 + l4 * 8);
#pragma unroll
    for (int i = 0; i < I; ++i)
#pragma unroll
      for (int j = 0; j < 4; ++j)
        acc[i][j] = __builtin_amdgcn_mfma_f32_16x16x32_bf16(af[i], bfr[j], acc[i][j], 0, 0, 0);
    __syncthreads();
  }

#pragma unroll
  for (int j = 0; j < 4; ++j) {
    int col = n0 + wc * 64 + j * 16 + l15;
    float bv_ = bias[col];
#pragma unroll
    for (int i = 0; i < I; ++i) {
#pragma unroll
      for (int rg = 0; rg < 4; ++rg) {
        int row = m0 + wr * (I * 16) + i * 16 + l4 * 4 + rg;
        float v = (acc[i][j][rg] + bv_) * osc;
        if (F32OUT) outf[(size_t)row * N + col] = v;
        else        outh[(size_t)row * N + col] = (bf16)v;
      }
    }
  }
}

// ---------------- V transpose: V[b*T+t][h*64+d] -> Vt[bh][d][t] ----------------
__global__ __launch_bounds__(256) void transpose_v(
    const bf16* __restrict__ V, bf16* __restrict__ Vt)
{
  __shared__ bf16 tile[64 * 68];
  const int tid = threadIdx.x;
  const int t0 = blockIdx.x << 6;
  const int bh = blockIdx.y;
  const bf16* vp = V + ((size_t)(bh >> 4) * 2048) * 1024 + (bh & 15) * 64;
  bf16* op = Vt + ((size_t)bh << 17);  // bh * 64 * 2048

#pragma unroll
  for (int it = 0; it < 2; ++it) {
    int c = it * 256 + tid;
    int row = c >> 3, gcol = (c & 7) * 8;
    bf16x8 v8 = *(const bf16x8*)(vp + (size_t)(t0 + row) * 1024 + gcol);
    // store as two 8B chunks (row stride 68 elems = 136 B, 8B-aligned)
    *(us4*)(&tile[row * 68 + gcol])     = *(us4*)&v8;
    *(us4*)(&tile[row * 68 + gcol + 4]) = ((us4*)&v8)[1];
  }
  __syncthreads();
#pragma unroll
  for (int it = 0; it < 2; ++it) {
    int u = it * 256 + tid;
    int d = u >> 3, ch = u & 7;
    us8 r;
#pragma unroll
    for (int jj = 0; jj < 8; ++jj)
      r[jj] = *(const unsigned short*)&tile[(ch * 8 + jj) * 68 + d];
    *(us8*)(op + (size_t)d * 2048 + t0 + ch * 8) = r;
  }
}

// ---------------- fused causal flash attention ----------------
// grid (16, 32): x -> q-tile PAIR (p, 31-p) => uniform 33 K-tiles/block.
// y -> b*16+h. 64 q-rows per tile (16/wave, Q in registers), K-tile 64,
// double-buffered K/Vt staging via global_load_lds, ONE barrier per tile.
// Row-sum via MFMA ones-trick. Q pre-scaled by 1/sqrt(Dh)*log2e.
__global__ __launch_bounds__(256, 3) void attn_kernel(
    const bf16* __restrict__ Q, const bf16* __restrict__ Kg,
    const bf16* __restrict__ Vt, bf16* __restrict__ AO)
{
  constexpr int T = 2048, C = 1024;
  __shared__ bf16 Ks[2][64 * 64];   // xor-swizzled 16B groups
  __shared__ bf16 Vts[2][64 * 64];  // xor-swizzled 16B groups
  __shared__ bf16 Ps[4][16 * 72];   // per-wave P (stride 72 -> aligned b128)

  const int tid = threadIdx.x;
  const int lane = tid & 63;
  const int w = tid >> 6;
  const int l15 = lane & 15, l4 = lane >> 4;

  const int p = blockIdx.x;
  const int bh = blockIdx.y;
  const size_t base = ((size_t)(bh >> 4) * T) * C + (bh & 15) * 64;
  const bf16* vtb = Vt + ((size_t)bh << 17);

  const bf16 one_h = (bf16)1.0f;
  const bf16x8 ones = {one_h, one_h, one_h, one_h, one_h, one_h, one_h, one_h};

  auto stageK = [&](int j0, int bufi) {
#pragma unroll
    for (int it = 0; it < 2; ++it) {
      int c = it * 256 + tid;
      int row = c >> 3, s = (c & 7) ^ (row & 7);
      gl2lds16(Kg + base + (size_t)(j0 + row) * C + s * 8, &Ks[bufi][c * 8]);
    }
  };
  auto stageV = [&](int j0, int bufi) {
#pragma unroll
    for (int it = 0; it < 2; ++it) {
      int c = it * 256 + tid;
      int row = c >> 3, s = (c & 7) ^ (row & 7);
      gl2lds16(vtb + ((size_t)row << 11) + j0 + s * 8, &Vts[bufi][c * 8]);
    }
  };

  const int qts[2] = { p, 31 - p };
  int g = 0;  // global tile counter -> buffer alternation
  stageK(0, 0);
  stageV(0, 0);

  for (int seg = 0; seg < 2; ++seg) {
    const int qt = qts[seg];
    const int q0 = qt << 6;
    const int nkt = qt + 1;

    // Q fragments in registers: wave w owns rows q0 + w*16 .. +15
    bf16x8 aq[2];
    {
      const bf16* qp = Q + base + (size_t)(q0 + w * 16 + l15) * C + l4 * 8;
      aq[0] = *(const bf16x8*)(qp);
      aq[1] = *(const bf16x8*)(qp + 32);
    }
    floatx4 o[4] = {};
    floatx4 lacc = {0.f, 0.f, 0.f, 0.f};
    float mrow[4] = {-1e38f, -1e38f, -1e38f, -1e38f};

    for (int jt = 0; jt < nkt; ++jt, ++g) {
      __syncthreads();  // staging of tile g visible; buf g^1 reads done
      const int cur = g & 1;
      if (jt + 1 < nkt) {
        stageK((jt + 1) << 6, cur ^ 1);
        stageV((jt + 1) << 6, cur ^ 1);
      } else if (seg == 0) {
        stageK(0, cur ^ 1);  // first tile of segment B
        stageV(0, cur ^ 1);
      }

      // ---- S = Q K^T (16 q-rows x 64 k-cols per wave) ----
      floatx4 s4[4] = {};
#pragma unroll
      for (int kk = 0; kk < 2; ++kk) {
        bf16x8 bk8[4];
#pragma unroll
        for (int tj = 0; tj < 4; ++tj) {
          int r = tj * 16 + l15;
          int sl = (kk * 4 + l4) ^ (r & 7);
          bk8[tj] = *(const bf16x8*)(&Ks[cur][r * 64 + sl * 8]);
        }
#pragma unroll
        for (int tj = 0; tj < 4; ++tj)
          s4[tj] = __builtin_amdgcn_mfma_f32_16x16x32_bf16(aq[kk], bk8[tj], s4[tj], 0, 0, 0);
      }

      // causal mask: only the diagonal tile
      if (jt == nkt - 1) {
        const int j0 = jt << 6;
        int qrowb = q0 + w * 16 + l4 * 4;
#pragma unroll
        for (int tj = 0; tj < 4; ++tj) {
          int kcol = j0 + tj * 16 + l15;
#pragma unroll
          for (int rg = 0; rg < 4; ++rg)
            if (kcol > qrowb + rg) s4[tj][rg] = -3e38f;
        }
      }

      // ---- online softmax: max via shuffles, sum via MFMA ones ----
#pragma unroll
      for (int rg = 0; rg < 4; ++rg) {
        float mx = fmaxf(fmaxf(s4[0][rg], s4[1][rg]), fmaxf(s4[2][rg], s4[3][rg]));
#pragma unroll
        for (int off = 1; off < 16; off <<= 1)
          mx = fmaxf(mx, __shfl_xor(mx, off, 64));
        float mnew = fmaxf(mrow[rg], mx);
        float al = __builtin_amdgcn_exp2f(mrow[rg] - mnew);
        mrow[rg] = mnew;
#pragma unroll
        for (int tj = 0; tj < 4; ++tj)
          s4[tj][rg] = __builtin_amdgcn_exp2f(s4[tj][rg] - mnew);
        lacc[rg] *= al;
#pragma unroll
        for (int td = 0; td < 4; ++td)
          o[td][rg] *= al;
      }

      // ---- P -> LDS (C layout -> A-operand layout) ----
#pragma unroll
      for (int tj = 0; tj < 4; ++tj)
#pragma unroll
        for (int rg = 0; rg < 4; ++rg)
          Ps[w][(l4 * 4 + rg) * 72 + tj * 16 + l15] = (bf16)s4[tj][rg];

      // ---- O += P V ; l += P . 1 ----
#pragma unroll
      for (int tk = 0; tk < 2; ++tk) {
        bf16x8 ap = *(const bf16x8*)(&Ps[w][l15 * 72 + tk * 32 + l4 * 8]);
        lacc = __builtin_amdgcn_mfma_f32_16x16x32_bf16(ap, ones, lacc, 0, 0, 0);
#pragma unroll
        for (int td = 0; td < 4; ++td) {
          int r = td * 16 + l15;
          int sl = (tk * 4 + l4) ^ (r & 7);
          bf16x8 bv8 = *(const bf16x8*)(&Vts[cur][r * 64 + sl * 8]);
          o[td] = __builtin_amdgcn_mfma_f32_16x16x32_bf16(ap, bv8, o[td], 0, 0, 0);
        }
      }
    }

    // epilogue: O / l -> AO (bf16)
#pragma unroll
    for (int rg = 0; rg < 4; ++rg) {
      float inv = 1.0f / lacc[rg];
      int qrow = q0 + w * 16 + l4 * 4 + rg;
#pragma unroll
      for (int td = 0; td < 4; ++td)
        AO[base + (size_t)qrow * C + td * 16 + l15] = (bf16)(o[td][rg] * inv);
    }
  }
}

// ---------------- launch ----------------
extern "C" void kernel_launch(void* const* d_in, const int* in_sizes, int n_in,
                              void* d_out, int out_size, void* d_ws, size_t ws_size,
                              hipStream_t stream) {
  const float* x  = (const float*)d_in[0];
  const float* Wq = (const float*)d_in[1];
  const float* bq = (const float*)d_in[2];
  const float* Wk = (const float*)d_in[3];
  const float* bk = (const float*)d_in[4];
  const float* Wv = (const float*)d_in[5];
  const float* bv = (const float*)d_in[6];
  const float* Wo = (const float*)d_in[7];
  const float* bo = (const float*)d_in[8];

  bf16* ws = (bf16*)d_ws;
  const size_t M1 = (size_t)1 << 20;
  bf16* xb  = ws;            // 4M (dead after QKV gemm; reused as Vt)
  bf16* Vtp = ws;            // 4M bf16 = 8 MB
  bf16* wqb = ws + 4 * M1;   // wq|wk|wv (1M each)
  bf16* wob = ws + 7 * M1;   // 1M
  bf16* Qp  = ws + 8 * M1;   // Q|K|V (4M each)
  bf16* AOp = ws + 20 * M1;  // 4M

  // 1) cast inputs to bf16
  cast_all<<<8192, 256, 0, stream>>>(x, Wq, Wk, Wv, Wo, ws);
  // 2) fused QKV projection (Q pre-scaled by 1/sqrt(64)*log2e)
  gemm_bt<false, true, 128><<<dim3(24, 32), 256, 0, stream>>>(
      xb, wqb, bq, bk, bv, (void*)Qp, 4096, 1024, 1024, 0.125f * LOG2E);
  // 3) V -> V^T per (b,h), into the dead xb region
  transpose_v<<<dim3(32, 32), 256, 0, stream>>>(Qp + 8 * M1, Vtp);
  // 4) causal flash attention (paired q-tiles, uniform load)
  attn_kernel<<<dim3(16, 32), 256, 0, stream>>>(Qp, Qp + 4 * M1, Vtp, AOp);
  // 5) output projection (fp32 out + bias)
  gemm_bt<true, false, 64><<<dim3(16, 32), 256, 0, stream>>>(
      AOp, wob, bo, nullptr, nullptr, d_out, 4096, 1024, 1024, 1.0f);
}

// Round 5
// 204.431 us; speedup vs baseline: 1.3909x; 1.0119x over previous
//
#include <hip/hip_runtime.h>
#include <hip/hip_bf16.h>

// MHA: B=2, T=2048, C=1024, H=16, Dh=64. fp32 in/out, bf16 MFMA internally.
// ws layout (bf16 elems): [0,4M): xb, later reused as Vt. [4M,7M): wq|wk|wv.
// [7M,8M): wo. [8M,20M): Q|K|V. [20M,24M): AO.  Total 48 MB.

typedef __bf16 bf16;
typedef __attribute__((ext_vector_type(8))) __bf16 bf16x8;
typedef __attribute__((ext_vector_type(4))) __bf16 bf16x4;
typedef __attribute__((ext_vector_type(4))) float floatx4;
typedef __attribute__((ext_vector_type(8))) unsigned short us8;
typedef __attribute__((ext_vector_type(4))) unsigned short us4;

#define LOG2E 1.44269504088896340736f

__device__ __forceinline__ void gl2lds16(const void* g, void* l) {
  __builtin_amdgcn_global_load_lds((const __attribute__((address_space(1))) void*)g,
                                   (__attribute__((address_space(3))) void*)l, 16, 0, 0);
}

// ---------------- cast fp32 -> bf16 (x | wq | wk | wv | wo) ----------------
__global__ __launch_bounds__(256) void cast_all(
    const float* __restrict__ x, const float* __restrict__ wq,
    const float* __restrict__ wk, const float* __restrict__ wv,
    const float* __restrict__ wo, bf16* __restrict__ dst)
{
  const size_t M1 = (size_t)1 << 20;
  size_t i4 = ((size_t)blockIdx.x * 256 + threadIdx.x) * 4;
  const float* src = x;
  size_t off = i4;
  if (i4 >= 4 * M1) {
    size_t r = i4 - 4 * M1;
    int seg = (int)(r >> 20);
    off = r & (M1 - 1);
    src = (seg == 0) ? wq : (seg == 1) ? wk : (seg == 2) ? wv : wo;
  }
  float4 f = *(const float4*)(src + off);
  bf16x4 o = { (bf16)f.x, (bf16)f.y, (bf16)f.z, (bf16)f.w };
  *(bf16x4*)(dst + i4) = o;
}

// ---------------- GEMM: out[m][n] = sum_k A[m][k]*W[n][k] + bias[n] ----------------
template<bool F32OUT, bool QKV, int BN>
__global__ __launch_bounds__(256, 2) void gemm_bt(
    const bf16* __restrict__ A, const bf16* __restrict__ Wb,
    const float* __restrict__ bq, const float* __restrict__ bk,
    const float* __restrict__ bv, void* __restrict__ outb,
    int M, int N, int K, float qscale)
{
  __shared__ bf16 As[128 * 32];
  __shared__ bf16 Bs[BN * 32];
  const int tid = threadIdx.x;
  const int lane = tid & 63;
  const int wid = tid >> 6;
  const int l15 = lane & 15, l4 = lane >> 4;
  constexpr int I = (BN == 128) ? 4 : 2;
  const int wr = (BN == 128) ? (wid >> 1) : wid;
  const int wc = (BN == 128) ? (wid & 1) : 0;

  const bf16* W;
  const float* bias;
  float osc = 1.0f;
  int n0;
  bf16* outh;
  float* outf;
  if (QKV) {
    int mat = blockIdx.x >> 3;
    n0 = (blockIdx.x & 7) << 7;
    W = Wb + ((size_t)mat << 20);
    bias = (mat == 0) ? bq : (mat == 1 ? bk : bv);
    if (mat == 0) osc = qscale;
    outh = (bf16*)outb + ((size_t)mat << 22);
    outf = nullptr;
  } else {
    n0 = blockIdx.x * BN;
    W = Wb;
    bias = bq;
    outf = (float*)outb;
    outh = nullptr;
  }
  const int m0 = blockIdx.y << 7;

  floatx4 acc[I][4] = {};

  for (int k0 = 0; k0 < K; k0 += 32) {
#pragma unroll
    for (int it = 0; it < 2; ++it) {
      int c = it * 256 + tid;
      int row = c >> 2, kof = (c & 3) << 3;
      gl2lds16(A + (size_t)(m0 + row) * K + k0 + kof, As + c * 8);
    }
#pragma unroll
    for (int it = 0; it < BN / 64; ++it) {
      int c = it * 256 + tid;
      int row = c >> 2, kof = (c & 3) << 3;
      gl2lds16(W + (size_t)(n0 + row) * K + k0 + kof, Bs + c * 8);
    }
    __syncthreads();
    bf16x8 af[I], bfr[4];
#pragma unroll
    for (int i = 0; i < I; ++i)
      af[i] = *(const bf16x8*)(As + (wr * (I * 16) + i * 16 + l15) * 32 + l4 * 8);
#pragma unroll
    for (int j = 0; j < 4; ++j)
      bfr[j] = *(const bf16x8*)(Bs + (wc * 64 + j * 16 + l15) * 32 + l4 * 8);
#pragma unroll
    for (int i = 0; i < I; ++i)
#pragma unroll
      for (int j = 0; j < 4; ++j)
        acc[i][j] = __builtin_amdgcn_mfma_f32_16x16x32_bf16(af[i], bfr[j], acc[i][j], 0, 0, 0);
    __syncthreads();
  }

#pragma unroll
  for (int j = 0; j < 4; ++j) {
    int col = n0 + wc * 64 + j * 16 + l15;
    float bv_ = bias[col];
#pragma unroll
    for (int i = 0; i < I; ++i) {
#pragma unroll
      for (int rg = 0; rg < 4; ++rg) {
        int row = m0 + wr * (I * 16) + i * 16 + l4 * 4 + rg;
        float v = (acc[i][j][rg] + bv_) * osc;
        if (F32OUT) outf[(size_t)row * N + col] = v;
        else        outh[(size_t)row * N + col] = (bf16)v;
      }
    }
  }
}

// ---------------- V transpose: V[b*T+t][h*64+d] -> Vt[bh][d][t] ----------------
__global__ __launch_bounds__(256) void transpose_v(
    const bf16* __restrict__ V, bf16* __restrict__ Vt)
{
  __shared__ bf16 tile[64 * 68];
  const int tid = threadIdx.x;
  const int t0 = blockIdx.x << 6;
  const int bh = blockIdx.y;
  const bf16* vp = V + ((size_t)(bh >> 4) * 2048) * 1024 + (bh & 15) * 64;
  bf16* op = Vt + ((size_t)bh << 17);  // bh * 64 * 2048

#pragma unroll
  for (int it = 0; it < 2; ++it) {
    int c = it * 256 + tid;
    int row = c >> 3, gcol = (c & 7) * 8;
    bf16x8 v8 = *(const bf16x8*)(vp + (size_t)(t0 + row) * 1024 + gcol);
    *(us4*)(&tile[row * 68 + gcol])     = *(us4*)&v8;
    *(us4*)(&tile[row * 68 + gcol + 4]) = ((us4*)&v8)[1];
  }
  __syncthreads();
#pragma unroll
  for (int it = 0; it < 2; ++it) {
    int u = it * 256 + tid;
    int d = u >> 3, ch = u & 7;
    us8 r;
#pragma unroll
    for (int jj = 0; jj < 8; ++jj)
      r[jj] = *(const unsigned short*)&tile[(ch * 8 + jj) * 68 + d];
    *(us8*)(op + (size_t)d * 2048 + t0 + ch * 8) = r;
  }
}

// ---------------- fused causal flash attention ----------------
// grid 512 1-D: bh = id&31 (fastest -> same head stays on one XCD),
// p = id>>5, qt = p<8 ? 15-p : p-8  (id and id+256 sum to uniform work).
// 128 q-rows/block, 32/wave. S computed TRANSPOSED (A=K, B=Q) so each lane
// owns whole q-rows (q = lane&15): in-register row stats + 2 shuffles,
// P packed to LDS as b64. K-tile 64, double-buffered gl2lds staging, one
// barrier per tile. Q pre-scaled by 1/sqrt(Dh)*log2e.
__global__ __launch_bounds__(256, 2) void attn_kernel(
    const bf16* __restrict__ Q, const bf16* __restrict__ Kg,
    const bf16* __restrict__ Vt, bf16* __restrict__ AO)
{
  constexpr int T = 2048, C = 1024;
  __shared__ bf16 Ks[2][64 * 64];   // [j][d], xor-swizzled 16B groups
  __shared__ bf16 Vts[2][64 * 64];  // [d][j], xor-swizzled 16B groups
  __shared__ bf16 Ps[4][32 * 72];   // per-wave P[q_local][j_local]

  const int tid = threadIdx.x;
  const int lane = tid & 63;
  const int w = tid >> 6;
  const int l15 = lane & 15, l4 = lane >> 4;

  const int u = blockIdx.x;
  const int bh = u & 31;
  const int p = u >> 5;
  const int qt = (p < 8) ? (15 - p) : (p - 8);
  const int q0 = qt << 7;
  const size_t base = ((size_t)(bh >> 4) * T) * C + (bh & 15) * 64;
  const bf16* vtb = Vt + ((size_t)bh << 17);

  // Q B-frags in registers: wave w owns rows q0 + w*32 .. +31
  bf16x8 qf[2][2];
#pragma unroll
  for (int tq = 0; tq < 2; ++tq) {
    const bf16* qp = Q + base + (size_t)(q0 + w * 32 + tq * 16 + l15) * C + l4 * 8;
    qf[tq][0] = *(const bf16x8*)(qp);
    qf[tq][1] = *(const bf16x8*)(qp + 32);
  }

  floatx4 o[2][4] = {};
  float mrow[2] = {-1e38f, -1e38f};
  float lrow[2] = {0.f, 0.f};

  auto stageK = [&](int j0, int bufi) {
#pragma unroll
    for (int it = 0; it < 2; ++it) {
      int c = it * 256 + tid;
      int row = c >> 3, s = (c & 7) ^ (row & 7);
      gl2lds16(Kg + base + (size_t)(j0 + row) * C + s * 8, &Ks[bufi][c * 8]);
    }
  };
  auto stageV = [&](int j0, int bufi) {
#pragma unroll
    for (int it = 0; it < 2; ++it) {
      int c = it * 256 + tid;
      int row = c >> 3, s = (c & 7) ^ (row & 7);
      gl2lds16(vtb + ((size_t)row << 11) + j0 + s * 8, &Vts[bufi][c * 8]);
    }
  };

  const int nkt = 2 * qt + 2;
  stageK(0, 0);
  stageV(0, 0);

  for (int jt = 0; jt < nkt; ++jt) {
    __syncthreads();  // staging of tile jt visible; buf jt^1 reads done
    const int cur = jt & 1;
    if (jt + 1 < nkt) {
      stageK((jt + 1) << 6, cur ^ 1);
      stageV((jt + 1) << 6, cur ^ 1);
    }
    const int j0 = jt << 6;
    const int qwave = q0 + w * 32;
    if (j0 <= qwave + 31) {  // wave-uniform: skip fully-masked tiles
      // ---- S^T = K Q^T : s4[tj][tq], row j = tj*16+l4*4+rg, col q = tq*16+l15
      floatx4 s4[4][2] = {};
#pragma unroll
      for (int kk = 0; kk < 2; ++kk) {
        bf16x8 kf[4];
#pragma unroll
        for (int tj = 0; tj < 4; ++tj) {
          int r = tj * 16 + l15;
          int sl = (kk * 4 + l4) ^ (r & 7);
          kf[tj] = *(const bf16x8*)(&Ks[cur][r * 64 + sl * 8]);
        }
#pragma unroll
        for (int tj = 0; tj < 4; ++tj)
#pragma unroll
          for (int tq = 0; tq < 2; ++tq)
            s4[tj][tq] = __builtin_amdgcn_mfma_f32_16x16x32_bf16(kf[tj], qf[tq][kk], s4[tj][tq], 0, 0, 0);
      }

      // ---- causal mask (j > q) — only near-diagonal tiles
      if (j0 + 63 > qwave) {
#pragma unroll
        for (int tj = 0; tj < 4; ++tj) {
          int j = j0 + tj * 16 + l4 * 4;
#pragma unroll
          for (int tq = 0; tq < 2; ++tq) {
            int q = qwave + tq * 16 + l15;
#pragma unroll
            for (int rg = 0; rg < 4; ++rg)
              if (j + rg > q) s4[tj][tq][rg] = -3e38f;
          }
        }
      }

      // ---- online softmax: each lane owns rows q (l15), stats in-register
      float al[2];
#pragma unroll
      for (int tq = 0; tq < 2; ++tq) {
        float mx = -3e38f;
#pragma unroll
        for (int tj = 0; tj < 4; ++tj)
#pragma unroll
          for (int rg = 0; rg < 4; ++rg)
            mx = fmaxf(mx, s4[tj][tq][rg]);
        mx = fmaxf(mx, __shfl_xor(mx, 16, 64));
        mx = fmaxf(mx, __shfl_xor(mx, 32, 64));
        float mnew = fmaxf(mrow[tq], mx);
        al[tq] = __builtin_amdgcn_exp2f(mrow[tq] - mnew);
        mrow[tq] = mnew;
        float psum = 0.f;
#pragma unroll
        for (int tj = 0; tj < 4; ++tj)
#pragma unroll
          for (int rg = 0; rg < 4; ++rg) {
            float e = __builtin_amdgcn_exp2f(s4[tj][tq][rg] - mnew);
            s4[tj][tq][rg] = e;
            psum += e;
          }
        psum += __shfl_xor(psum, 16, 64);
        psum += __shfl_xor(psum, 32, 64);
        lrow[tq] = lrow[tq] * al[tq] + psum;
      }

      // ---- P -> LDS, packed b64 (rg contiguous): Ps[q_local][j_local]
#pragma unroll
      for (int tq = 0; tq < 2; ++tq)
#pragma unroll
        for (int tj = 0; tj < 4; ++tj) {
          bf16x4 pk = { (bf16)s4[tj][tq][0], (bf16)s4[tj][tq][1],
                        (bf16)s4[tj][tq][2], (bf16)s4[tj][tq][3] };
          *(bf16x4*)(&Ps[w][(tq * 16 + l15) * 72 + tj * 16 + l4 * 4]) = pk;
        }

      // ---- rescale O by alpha (broadcast lane l15=q -> O rows l4*4+rg)
#pragma unroll
      for (int tm = 0; tm < 2; ++tm)
#pragma unroll
        for (int rg = 0; rg < 4; ++rg) {
          float aO = __shfl(al[tm], l4 * 4 + rg, 64);
#pragma unroll
          for (int td = 0; td < 4; ++td)
            o[tm][td][rg] *= aO;
        }

      // ---- O += P V  (A = P from LDS, B = V^T)
#pragma unroll
      for (int tk = 0; tk < 2; ++tk) {
        bf16x8 pf[2];
#pragma unroll
        for (int tm = 0; tm < 2; ++tm)
          pf[tm] = *(const bf16x8*)(&Ps[w][(tm * 16 + l15) * 72 + tk * 32 + l4 * 8]);
#pragma unroll
        for (int td = 0; td < 4; ++td) {
          int r = td * 16 + l15;
          int sl = (tk * 4 + l4) ^ (r & 7);
          bf16x8 vf = *(const bf16x8*)(&Vts[cur][r * 64 + sl * 8]);
#pragma unroll
          for (int tm = 0; tm < 2; ++tm)
            o[tm][td] = __builtin_amdgcn_mfma_f32_16x16x32_bf16(pf[tm], vf, o[tm][td], 0, 0, 0);
        }
      }
    }
  }

  // ---- epilogue: O / l -> AO (bf16)
  float inv[2] = { 1.0f / lrow[0], 1.0f / lrow[1] };
#pragma unroll
  for (int tm = 0; tm < 2; ++tm)
#pragma unroll
    for (int rg = 0; rg < 4; ++rg) {
      float iv = __shfl(inv[tm], l4 * 4 + rg, 64);
      int qrow = q0 + w * 32 + tm * 16 + l4 * 4 + rg;
#pragma unroll
      for (int td = 0; td < 4; ++td)
        AO[base + (size_t)qrow * C + td * 16 + l15] = (bf16)(o[tm][td][rg] * iv);
    }
}

// ---------------- launch ----------------
extern "C" void kernel_launch(void* const* d_in, const int* in_sizes, int n_in,
                              void* d_out, int out_size, void* d_ws, size_t ws_size,
                              hipStream_t stream) {
  const float* x  = (const float*)d_in[0];
  const float* Wq = (const float*)d_in[1];
  const float* bq = (const float*)d_in[2];
  const float* Wk = (const float*)d_in[3];
  const float* bk = (const float*)d_in[4];
  const float* Wv = (const float*)d_in[5];
  const float* bv = (const float*)d_in[6];
  const float* Wo = (const float*)d_in[7];
  const float* bo = (const float*)d_in[8];

  bf16* ws = (bf16*)d_ws;
  const size_t M1 = (size_t)1 << 20;
  bf16* xb  = ws;            // 4M (dead after QKV gemm; reused as Vt)
  bf16* Vtp = ws;            // 4M bf16 = 8 MB
  bf16* wqb = ws + 4 * M1;   // wq|wk|wv (1M each)
  bf16* wob = ws + 7 * M1;   // 1M
  bf16* Qp  = ws + 8 * M1;   // Q|K|V (4M each)
  bf16* AOp = ws + 20 * M1;  // 4M

  // 1) cast inputs to bf16
  cast_all<<<8192, 256, 0, stream>>>(x, Wq, Wk, Wv, Wo, ws);
  // 2) fused QKV projection (Q pre-scaled by 1/sqrt(64)*log2e)
  gemm_bt<false, true, 128><<<dim3(24, 32), 256, 0, stream>>>(
      xb, wqb, bq, bk, bv, (void*)Qp, 4096, 1024, 1024, 0.125f * LOG2E);
  // 3) V -> V^T per (b,h), into the dead xb region
  transpose_v<<<dim3(32, 32), 256, 0, stream>>>(Qp + 8 * M1, Vtp);
  // 4) causal flash attention (128q blocks, S^T layout, bh-major for XCD/L2)
  attn_kernel<<<512, 256, 0, stream>>>(Qp, Qp + 4 * M1, Vtp, AOp);
  // 5) output projection (fp32 out + bias)
  gemm_bt<true, false, 64><<<dim3(16, 32), 256, 0, stream>>>(
      AOp, wob, bo, nullptr, nullptr, d_out, 4096, 1024, 1024, 1.0f);
}

// Round 6
// 185.820 us; speedup vs baseline: 1.5302x; 1.1002x over previous
//
#include <hip/hip_runtime.h>
#include <hip/hip_bf16.h>

// MHA: B=2, T=2048, C=1024, H=16, Dh=64. fp32 in/out, bf16 MFMA internally.
// ws layout (bf16 elems): [0,4M): xb. [4M,7M): wq|wk|wv. [7M,8M): wo.
// [8M,12M): Q. [12M,16M): K. [16M,20M): Vt (written by QKV gemm epilogue).
// [20M,24M): AO.  Total 48 MB.

typedef __bf16 bf16;
typedef __attribute__((ext_vector_type(8))) __bf16 bf16x8;
typedef __attribute__((ext_vector_type(4))) __bf16 bf16x4;
typedef __attribute__((ext_vector_type(4))) float floatx4;

#define LOG2E 1.44269504088896340736f

__device__ __forceinline__ void gl2lds16(const void* g, void* l) {
  __builtin_amdgcn_global_load_lds((const __attribute__((address_space(1))) void*)g,
                                   (__attribute__((address_space(3))) void*)l, 16, 0, 0);
}

// ---------------- cast fp32 -> bf16 (x | wq | wk | wv | wo) ----------------
__global__ __launch_bounds__(256) void cast_all(
    const float* __restrict__ x, const float* __restrict__ wq,
    const float* __restrict__ wk, const float* __restrict__ wv,
    const float* __restrict__ wo, bf16* __restrict__ dst)
{
  const size_t M1 = (size_t)1 << 20;
  size_t i4 = ((size_t)blockIdx.x * 256 + threadIdx.x) * 4;
  const float* src = x;
  size_t off = i4;
  if (i4 >= 4 * M1) {
    size_t r = i4 - 4 * M1;
    int seg = (int)(r >> 20);
    off = r & (M1 - 1);
    src = (seg == 0) ? wq : (seg == 1) ? wk : (seg == 2) ? wv : wo;
  }
  float4 f = *(const float4*)(src + off);
  bf16x4 o = { (bf16)f.x, (bf16)f.y, (bf16)f.z, (bf16)f.w };
  *(bf16x4*)(dst + i4) = o;
}

// ---------------- GEMM: out[m][n] = sum_k A[m][k]*W[n][k] + bias[n] ----------------
// QKV: mat0 -> Q (bf16, pre-scaled), mat1 -> K (bf16), mat2 -> Vt (bf16,
// written transposed per head: Vt[bh][d][t]). Non-QKV: fp32 out + bias.
template<bool F32OUT, bool QKV, int BN>
__global__ __launch_bounds__(256, 2) void gemm_bt(
    const bf16* __restrict__ A, const bf16* __restrict__ Wb,
    const float* __restrict__ bq, const float* __restrict__ bk,
    const float* __restrict__ bv, void* __restrict__ outb,
    bf16* __restrict__ vt, int M, int N, int K, float qscale)
{
  __shared__ bf16 As[128 * 32];
  __shared__ bf16 Bs[BN * 32];
  const int tid = threadIdx.x;
  const int lane = tid & 63;
  const int wid = tid >> 6;
  const int l15 = lane & 15, l4 = lane >> 4;
  constexpr int I = (BN == 128) ? 4 : 2;
  const int wr = (BN == 128) ? (wid >> 1) : wid;
  const int wc = (BN == 128) ? (wid & 1) : 0;

  const bf16* W;
  const float* bias;
  float osc = 1.0f;
  int n0, mat = 0;
  bf16* outh;
  float* outf;
  if (QKV) {
    mat = blockIdx.x >> 3;
    n0 = (blockIdx.x & 7) << 7;
    W = Wb + ((size_t)mat << 20);
    bias = (mat == 0) ? bq : (mat == 1 ? bk : bv);
    if (mat == 0) osc = qscale;
    outh = (bf16*)outb + ((size_t)mat << 22);
    outf = nullptr;
  } else {
    n0 = blockIdx.x * BN;
    W = Wb;
    bias = bq;
    outf = (float*)outb;
    outh = nullptr;
  }
  const int m0 = blockIdx.y << 7;

  floatx4 acc[I][4] = {};

  for (int k0 = 0; k0 < K; k0 += 32) {
#pragma unroll
    for (int it = 0; it < 2; ++it) {
      int c = it * 256 + tid;
      int row = c >> 2, kof = (c & 3) << 3;
      gl2lds16(A + (size_t)(m0 + row) * K + k0 + kof, As + c * 8);
    }
#pragma unroll
    for (int it = 0; it < BN / 64; ++it) {
      int c = it * 256 + tid;
      int row = c >> 2, kof = (c & 3) << 3;
      gl2lds16(W + (size_t)(n0 + row) * K + k0 + kof, Bs + c * 8);
    }
    __syncthreads();
    bf16x8 af[I], bfr[4];
#pragma unroll
    for (int i = 0; i < I; ++i)
      af[i] = *(const bf16x8*)(As + (wr * (I * 16) + i * 16 + l15) * 32 + l4 * 8);
#pragma unroll
    for (int j = 0; j < 4; ++j)
      bfr[j] = *(const bf16x8*)(Bs + (wc * 64 + j * 16 + l15) * 32 + l4 * 8);
#pragma unroll
    for (int i = 0; i < I; ++i)
#pragma unroll
      for (int j = 0; j < 4; ++j)
        acc[i][j] = __builtin_amdgcn_mfma_f32_16x16x32_bf16(af[i], bfr[j], acc[i][j], 0, 0, 0);
    __syncthreads();
  }

  if (QKV && mat == 2) {
    // write Vt[bh][d][t]: lane's 4 rg rows are contiguous t -> b64 stores
#pragma unroll
    for (int j = 0; j < 4; ++j) {
      int col = n0 + wc * 64 + j * 16 + l15;
      float bv_ = bias[col];
      int h = col >> 6, d = col & 63;
#pragma unroll
      for (int i = 0; i < I; ++i) {
        int row = m0 + wr * (I * 16) + i * 16 + l4 * 4;
        int bb = row >> 11, t = row & 2047;
        bf16x4 pk;
#pragma unroll
        for (int rg = 0; rg < 4; ++rg) pk[rg] = (bf16)(acc[i][j][rg] + bv_);
        *(bf16x4*)(vt + (((size_t)(bb * 16 + h)) << 17) + ((size_t)d << 11) + t) = pk;
      }
    }
    return;
  }

#pragma unroll
  for (int j = 0; j < 4; ++j) {
    int col = n0 + wc * 64 + j * 16 + l15;
    float bv_ = bias[col];
#pragma unroll
    for (int i = 0; i < I; ++i) {
#pragma unroll
      for (int rg = 0; rg < 4; ++rg) {
        int row = m0 + wr * (I * 16) + i * 16 + l4 * 4 + rg;
        float v = (acc[i][j][rg] + bv_) * osc;
        if (F32OUT) outf[(size_t)row * N + col] = v;
        else        outh[(size_t)row * N + col] = (bf16)v;
      }
    }
  }
}

// ---------------- fused causal flash attention ----------------
// grid 1024 1-D: bh = u&31 (fastest -> head-local L2/XCD), qt = 31-(u>>5)
// (heavy first, dynamic balancing across ~3 resident blocks/CU).
// 64 q-rows/block (16/wave, Q in registers as B-frags). S computed
// TRANSPOSED (A=K, B=Q) so each lane owns a whole q-row: in-register
// softmax stats + 2 shuffles. O computed TRANSPOSED (A=Vt, B=P) so
// alpha/1-over-l are per-lane and the epilogue is b64 stores. K-tile 64,
// double-buffered K/Vt gl2lds staging, ONE barrier per tile.
// Q pre-scaled by 1/sqrt(Dh)*log2e.
__global__ __launch_bounds__(256, 3) void attn_kernel(
    const bf16* __restrict__ Q, const bf16* __restrict__ Kg,
    const bf16* __restrict__ Vt, bf16* __restrict__ AO)
{
  constexpr int T = 2048, C = 1024;
  __shared__ bf16 Ks[2][64 * 64];   // [j][d], xor-swizzled 16B groups
  __shared__ bf16 Vts[2][64 * 64];  // [d][j], xor-swizzled 16B groups
  __shared__ bf16 Ps[4][16 * 80];   // per-wave P[q_local][j_local]

  const int tid = threadIdx.x;
  const int lane = tid & 63;
  const int w = tid >> 6;
  const int l15 = lane & 15, l4 = lane >> 4;

  const int u = blockIdx.x;
  const int bh = u & 31;
  const int qt = 31 - (u >> 5);
  const int q0 = qt << 6;
  const size_t base = ((size_t)(bh >> 4) * T) * C + (bh & 15) * 64;
  const bf16* vtb = Vt + ((size_t)bh << 17);

  const int q = q0 + w * 16 + l15;  // this lane's q-row (as S^T/O^T column)

  // Q B-frags in registers
  bf16x8 qf[2];
  {
    const bf16* qp = Q + base + (size_t)q * C + l4 * 8;
    qf[0] = *(const bf16x8*)(qp);
    qf[1] = *(const bf16x8*)(qp + 32);
  }

  floatx4 o[4] = {};       // O^T: rows d = td*16+l4*4+rg, col q = l15
  float mrow = -1e38f, lrow = 0.f;

  auto stageK = [&](int j0, int bufi) {
#pragma unroll
    for (int it = 0; it < 2; ++it) {
      int c = it * 256 + tid;
      int row = c >> 3, s = (c & 7) ^ (row & 7);
      gl2lds16(Kg + base + (size_t)(j0 + row) * C + s * 8, &Ks[bufi][c * 8]);
    }
  };
  auto stageV = [&](int j0, int bufi) {
#pragma unroll
    for (int it = 0; it < 2; ++it) {
      int c = it * 256 + tid;
      int row = c >> 3, s = (c & 7) ^ (row & 7);
      gl2lds16(vtb + ((size_t)row << 11) + j0 + s * 8, &Vts[bufi][c * 8]);
    }
  };

  const int nkt = qt + 1;
  stageK(0, 0);
  stageV(0, 0);

  for (int jt = 0; jt < nkt; ++jt) {
    __syncthreads();  // staging of tile jt visible; buf jt^1 reads done
    const int cur = jt & 1;
    if (jt + 1 < nkt) {
      stageK((jt + 1) << 6, cur ^ 1);
      stageV((jt + 1) << 6, cur ^ 1);
    }
    const int j0 = jt << 6;

    // ---- S^T = K Q^T : s4[tj], row j = tj*16+l4*4+rg, col q = l15
    floatx4 s4[4] = {};
#pragma unroll
    for (int kk = 0; kk < 2; ++kk) {
      bf16x8 kf[4];
#pragma unroll
      for (int tj = 0; tj < 4; ++tj) {
        int r = tj * 16 + l15;
        int sl = (kk * 4 + l4) ^ (r & 7);
        kf[tj] = *(const bf16x8*)(&Ks[cur][r * 64 + sl * 8]);
      }
#pragma unroll
      for (int tj = 0; tj < 4; ++tj)
        s4[tj] = __builtin_amdgcn_mfma_f32_16x16x32_bf16(kf[tj], qf[kk], s4[tj], 0, 0, 0);
    }

    // ---- causal mask (j > q): only the diagonal (last) tile
    if (jt == nkt - 1) {
#pragma unroll
      for (int tj = 0; tj < 4; ++tj) {
        int j = j0 + tj * 16 + l4 * 4;
#pragma unroll
        for (int rg = 0; rg < 4; ++rg)
          if (j + rg > q) s4[tj][rg] = -3e38f;
      }
    }

    // ---- online softmax: lane owns row q, stats in-register + 2 shuffles
    float mx = -3e38f;
#pragma unroll
    for (int tj = 0; tj < 4; ++tj)
#pragma unroll
      for (int rg = 0; rg < 4; ++rg)
        mx = fmaxf(mx, s4[tj][rg]);
    mx = fmaxf(mx, __shfl_xor(mx, 16, 64));
    mx = fmaxf(mx, __shfl_xor(mx, 32, 64));
    float mnew = fmaxf(mrow, mx);
    float al = __builtin_amdgcn_exp2f(mrow - mnew);
    mrow = mnew;
    float psum = 0.f;
#pragma unroll
    for (int tj = 0; tj < 4; ++tj)
#pragma unroll
      for (int rg = 0; rg < 4; ++rg) {
        float e = __builtin_amdgcn_exp2f(s4[tj][rg] - mnew);
        s4[tj][rg] = e;
        psum += e;
      }
    psum += __shfl_xor(psum, 16, 64);
    psum += __shfl_xor(psum, 32, 64);
    lrow = lrow * al + psum;

    // ---- P -> LDS, packed b64 (rg contiguous): Ps[q_local][j_local]
#pragma unroll
    for (int tj = 0; tj < 4; ++tj) {
      bf16x4 pk = { (bf16)s4[tj][0], (bf16)s4[tj][1],
                    (bf16)s4[tj][2], (bf16)s4[tj][3] };
      *(bf16x4*)(&Ps[w][l15 * 80 + tj * 16 + l4 * 4]) = pk;
    }

    // ---- rescale O^T by alpha (col q = l15 -> per-lane, no shuffles)
#pragma unroll
    for (int td = 0; td < 4; ++td)
#pragma unroll
      for (int rg = 0; rg < 4; ++rg)
        o[td][rg] *= al;

    // ---- O^T += Vt P^T  (A = Vt frag, B = P^T frag; same LDS reads)
#pragma unroll
    for (int tk = 0; tk < 2; ++tk) {
      bf16x8 pf = *(const bf16x8*)(&Ps[w][l15 * 80 + tk * 32 + l4 * 8]);
#pragma unroll
      for (int td = 0; td < 4; ++td) {
        int r = td * 16 + l15;
        int sl = (tk * 4 + l4) ^ (r & 7);
        bf16x8 vf = *(const bf16x8*)(&Vts[cur][r * 64 + sl * 8]);
        o[td] = __builtin_amdgcn_mfma_f32_16x16x32_bf16(vf, pf, o[td], 0, 0, 0);
      }
    }
  }

  // ---- epilogue: O^T / l -> AO[q][d], b64 stores, all per-lane
  float inv = 1.0f / lrow;
#pragma unroll
  for (int td = 0; td < 4; ++td) {
    bf16x4 ok = { (bf16)(o[td][0] * inv), (bf16)(o[td][1] * inv),
                  (bf16)(o[td][2] * inv), (bf16)(o[td][3] * inv) };
    *(bf16x4*)(AO + base + (size_t)q * C + td * 16 + l4 * 4) = ok;
  }
}

// ---------------- launch ----------------
extern "C" void kernel_launch(void* const* d_in, const int* in_sizes, int n_in,
                              void* d_out, int out_size, void* d_ws, size_t ws_size,
                              hipStream_t stream) {
  const float* x  = (const float*)d_in[0];
  const float* Wq = (const float*)d_in[1];
  const float* bq = (const float*)d_in[2];
  const float* Wk = (const float*)d_in[3];
  const float* bk = (const float*)d_in[4];
  const float* Wv = (const float*)d_in[5];
  const float* bv = (const float*)d_in[6];
  const float* Wo = (const float*)d_in[7];
  const float* bo = (const float*)d_in[8];

  bf16* ws = (bf16*)d_ws;
  const size_t M1 = (size_t)1 << 20;
  bf16* xb  = ws;            // 4M
  bf16* wqb = ws + 4 * M1;   // wq|wk|wv (1M each)
  bf16* wob = ws + 7 * M1;   // 1M
  bf16* Qp  = ws + 8 * M1;   // Q (4M) | K (4M)
  bf16* Vtp = ws + 16 * M1;  // Vt (4M), written by QKV gemm epilogue
  bf16* AOp = ws + 20 * M1;  // 4M

  // 1) cast inputs to bf16
  cast_all<<<8192, 256, 0, stream>>>(x, Wq, Wk, Wv, Wo, ws);
  // 2) fused QKV projection (Q pre-scaled; V written transposed to Vtp)
  gemm_bt<false, true, 128><<<dim3(24, 32), 256, 0, stream>>>(
      xb, wqb, bq, bk, bv, (void*)Qp, Vtp, 4096, 1024, 1024, 0.125f * LOG2E);
  // 3) causal flash attention (64q blocks, S^T+O^T layout, bh-major)
  attn_kernel<<<1024, 256, 0, stream>>>(Qp, Qp + 4 * M1, Vtp, AOp);
  // 4) output projection (fp32 out + bias)
  gemm_bt<true, false, 64><<<dim3(16, 32), 256, 0, stream>>>(
      AOp, wob, bo, nullptr, nullptr, d_out, nullptr, 4096, 1024, 1024, 1.0f);
}